// Round 6
// baseline (142.373 us; speedup 1.0000x reference)
//
#include <hip/hip_runtime.h>

#define IN_DIM  65536
#define OUT_DIM 65536
#define BATCH   256

// ws layout: float4 coeffs[OUT_DIM] @256 ; uint x_Tb[IN_DIM * BATCH/2] @2MiB (packed bf16 pairs).

__device__ __forceinline__ float bf2f(unsigned short h) {
    return __uint_as_float(((unsigned int)h) << 16);
}
__device__ __forceinline__ unsigned short f2bf(float f) {
    unsigned int u = __float_as_uint(f);
    u += 0x7FFFu + ((u >> 16) & 1u);
    return (unsigned short)(u >> 16);
}

// Softmax over 16 logits collapsed to affine coeffs of out = w0 + w1*a + w2*b + w3*ab.
__device__ __forceinline__ float4 collapse16(const float* w) {
    float m = w[0];
    #pragma unroll
    for (int f = 1; f < 16; ++f) m = fmaxf(m, w[f]);
    float e[16]; float sum = 0.f;
    #pragma unroll
    for (int f = 0; f < 16; ++f) { e[f] = __expf(w[f] - m); sum += e[f]; }
    float inv = 1.0f / sum;
    float w0 = e[8] + e[9] + e[10] + e[11] + e[12] + e[13] + e[14] + e[15];
    float w1 = (e[2] + e[3] + e[6] + e[7]) - (e[8] + e[9] + e[12] + e[13]);
    float w2 = (e[4] + e[5] + e[6] + e[7]) - (e[8] + e[9] + e[10] + e[11]);
    float w3 = e[1] - e[2] - e[4] - 2.f*e[6] - e[7]
             + e[8] + 2.f*e[9] + e[11] + e[13] - e[14];
    return make_float4(w0 * inv, w1 * inv, w2 * inv, w3 * inv);
}

#define TRANS_BLOCKS ((IN_DIM / 64) * (BATCH / 64))   // 4096
#define COEFF_BLOCKS (OUT_DIM / 256)                  // 256
#define PAD 69   // 69 % 32 = 5 -> column-phase reads are <=2-way (free)

// ---------------------------------------------------------------------------
// Kernel A: fused transpose (x [BATCH,IN_DIM] -> packed-bf16 x_Tb
// [IN_DIM, BATCH/2 dwords]) + per-neuron softmax-collapse coeffs.
// Vectorized: float4/uint2 global loads, uint4 packed stores.
// Each block self-detects the dtype of the input it touches.
// ---------------------------------------------------------------------------
__global__ __launch_bounds__(256) void prep_kernel(
    const void* __restrict__ x_raw,       // [BATCH, IN_DIM] fp32 or bf16
    const void* __restrict__ w_raw,       // [OUT_DIM, 16]   fp32 or bf16
    unsigned int* __restrict__ x_Tb,      // [IN_DIM, BATCH/2] packed bf16
    float4* __restrict__ coeffs,          // [OUT_DIM]
    int trans_blocks)
{
    __shared__ float tile[64][PAD];       // [batch_row][col]
    __shared__ int sflag;
    int t  = threadIdx.x;
    int bx = blockIdx.x;

    if (bx < trans_blocks) {
        if (t == 0) sflag = 0;
        __syncthreads();
        if (((const unsigned short*)x_raw)[t] >= 0x3F80u) atomicOr(&sflag, 1);
        __syncthreads();
        int x_is_f32 = sflag;

        int c0 = (bx >> 2) * 64;   // input-dim tile
        int b0 = (bx & 3) * 64;    // batch tile
        int cq = t & 15;           // float4 col group (4 cols)
        int r  = t >> 4;           // 0..15

        if (x_is_f32) {
            const float4* x4 = (const float4*)x_raw;
            #pragma unroll
            for (int k = 0; k < 4; ++k) {
                int row = r + 16 * k;
                float4 v = x4[(size_t)(b0 + row) * (IN_DIM / 4) + (c0 >> 2) + cq];
                tile[row][4 * cq + 0] = v.x;
                tile[row][4 * cq + 1] = v.y;
                tile[row][4 * cq + 2] = v.z;
                tile[row][4 * cq + 3] = v.w;
            }
        } else {
            const uint2* x2 = (const uint2*)x_raw;  // 4 bf16 per uint2
            #pragma unroll
            for (int k = 0; k < 4; ++k) {
                int row = r + 16 * k;
                uint2 v = x2[(size_t)(b0 + row) * (IN_DIM / 4) + (c0 >> 2) + cq];
                tile[row][4 * cq + 0] = bf2f((unsigned short)(v.x & 0xFFFFu));
                tile[row][4 * cq + 1] = bf2f((unsigned short)(v.x >> 16));
                tile[row][4 * cq + 2] = bf2f((unsigned short)(v.y & 0xFFFFu));
                tile[row][4 * cq + 3] = bf2f((unsigned short)(v.y >> 16));
            }
        }
        __syncthreads();

        // pack columns: per col, 32 dwords (64 batch) = 8 uint4; 512 uint4/tile
        uint4* dst = (uint4*)x_Tb;
        int q   = t & 7;          // uint4 index within col (batch 8q..8q+7)
        int col = t >> 3;         // 0..31, second iter +32
        #pragma unroll
        for (int it = 0; it < 2; ++it) {
            int cc = col + 32 * it;
            unsigned int d[4];
            #pragma unroll
            for (int j = 0; j < 4; ++j) {
                float lo = tile[8 * q + 2 * j][cc];
                float hi = tile[8 * q + 2 * j + 1][cc];
                d[j] = (unsigned int)f2bf(lo) | ((unsigned int)f2bf(hi) << 16);
            }
            dst[(size_t)(c0 + cc) * (BATCH / 8) + (b0 >> 3) + q] =
                make_uint4(d[0], d[1], d[2], d[3]);
        }
    } else {
        // ---- coeff block ----
        if (t == 0) sflag = 0;
        __syncthreads();
        if ((((const unsigned short*)w_raw)[t] & 0x7FFFu) >= 0x4800u) atomicOr(&sflag, 1);
        __syncthreads();
        int w_is_f32 = sflag;

        int o = (bx - trans_blocks) * 256 + t;
        if (o >= OUT_DIM) return;

        float w[16];
        if (w_is_f32) {
            const float4* w4 = reinterpret_cast<const float4*>(w_raw) + (size_t)o * 4;
            float4 q0 = w4[0], q1 = w4[1], q2 = w4[2], q3 = w4[3];
            w[0]=q0.x; w[1]=q0.y; w[2]=q0.z; w[3]=q0.w;
            w[4]=q1.x; w[5]=q1.y; w[6]=q1.z; w[7]=q1.w;
            w[8]=q2.x; w[9]=q2.y; w[10]=q2.z; w[11]=q2.w;
            w[12]=q3.x; w[13]=q3.y; w[14]=q3.z; w[15]=q3.w;
        } else {
            const uint4* w16 = reinterpret_cast<const uint4*>(
                (const unsigned short*)w_raw + (size_t)o * 16);
            uint4 p0 = w16[0], p1 = w16[1];
            unsigned int pk[8] = { p0.x, p0.y, p0.z, p0.w, p1.x, p1.y, p1.z, p1.w };
            #pragma unroll
            for (int i = 0; i < 8; ++i) {
                w[2*i]   = bf2f((unsigned short)(pk[i] & 0xFFFFu));
                w[2*i+1] = bf2f((unsigned short)(pk[i] >> 16));
            }
        }
        coeffs[o] = collapse16(w);
    }
}

// ---------------------------------------------------------------------------
// Kernel B: gather + affine combine from packed-bf16 x_Tb.
// 2 neurons per thread, 32 batch rows per block-y: 16 independent uint4
// gathers in flight (each = one full 64B line); float2 stores.
// ---------------------------------------------------------------------------
__global__ __launch_bounds__(256) void logic_bt_kernel(
    const unsigned int* __restrict__ x_Tb,  // [IN_DIM, BATCH/2]
    const void* __restrict__ idx_raw,       // [2, OUT_DIM] int32 or int64
    const float4* __restrict__ coeffs,
    float* __restrict__ out)                // [BATCH, OUT_DIM]
{
    __shared__ int sflag;
    int t = threadIdx.x;
    if (t == 0) sflag = 0;
    __syncthreads();
    if ((t & 1) && ((const int*)idx_raw)[t] != 0) atomicOr(&sflag, 1);
    __syncthreads();
    int idx_is_i32 = sflag;   // odd dwords nonzero -> int32

    int o0 = blockIdx.x * 512 + 2 * t;
    int o1 = o0 + 1;
    int ia0, ib0, ia1, ib1;
    if (idx_is_i32) {
        const int* p = (const int*)idx_raw;
        ia0 = p[o0];           ia1 = p[o1];
        ib0 = p[OUT_DIM + o0]; ib1 = p[OUT_DIM + o1];
    } else {
        const long long* p = (const long long*)idx_raw;
        ia0 = (int)p[o0];           ia1 = (int)p[o1];
        ib0 = (int)p[OUT_DIM + o0]; ib1 = (int)p[OUT_DIM + o1];
    }
    float4 c0 = coeffs[o0];
    float4 c1 = coeffs[o1];

    int b0 = blockIdx.y * 32;
    int qo = b0 >> 3;                       // uint4 offset within row
    const uint4* A0 = (const uint4*)x_Tb + ((size_t)ia0 << 5) + qo;
    const uint4* B0 = (const uint4*)x_Tb + ((size_t)ib0 << 5) + qo;
    const uint4* A1 = (const uint4*)x_Tb + ((size_t)ia1 << 5) + qo;
    const uint4* B1 = (const uint4*)x_Tb + ((size_t)ib1 << 5) + qo;

    uint4 a0[4], v0[4], a1[4], v1[4];
    #pragma unroll
    for (int r = 0; r < 4; ++r) {
        a0[r] = A0[r]; v0[r] = B0[r];
        a1[r] = A1[r]; v1[r] = B1[r];
    }

    float2* out2 = (float2*)(out + o0);     // o0 even -> 8B aligned

    #pragma unroll
    for (int r = 0; r < 4; ++r) {
        unsigned int pa0[4] = { a0[r].x, a0[r].y, a0[r].z, a0[r].w };
        unsigned int pb0[4] = { v0[r].x, v0[r].y, v0[r].z, v0[r].w };
        unsigned int pa1[4] = { a1[r].x, a1[r].y, a1[r].z, a1[r].w };
        unsigned int pb1[4] = { v1[r].x, v1[r].y, v1[r].z, v1[r].w };
        int base = b0 + r * 8;
        #pragma unroll
        for (int j = 0; j < 4; ++j) {
            float xa0 = bf2f((unsigned short)(pa0[j] & 0xFFFFu));
            float ya0 = bf2f((unsigned short)(pa0[j] >> 16));
            float xb0 = bf2f((unsigned short)(pb0[j] & 0xFFFFu));
            float yb0 = bf2f((unsigned short)(pb0[j] >> 16));
            float xa1 = bf2f((unsigned short)(pa1[j] & 0xFFFFu));
            float ya1 = bf2f((unsigned short)(pa1[j] >> 16));
            float xb1 = bf2f((unsigned short)(pb1[j] & 0xFFFFu));
            float yb1 = bf2f((unsigned short)(pb1[j] >> 16));

            float2 r0, r1;
            r0.x = fmaf(xb0, fmaf(c0.w, xa0, c0.z), fmaf(c0.y, xa0, c0.x));
            r0.y = fmaf(xb1, fmaf(c1.w, xa1, c1.z), fmaf(c1.y, xa1, c1.x));
            r1.x = fmaf(yb0, fmaf(c0.w, ya0, c0.z), fmaf(c0.y, ya0, c0.x));
            r1.y = fmaf(yb1, fmaf(c1.w, ya1, c1.z), fmaf(c1.y, ya1, c1.x));

            out2[(size_t)(base + 2 * j)     * (OUT_DIM / 2)] = r0;
            out2[(size_t)(base + 2 * j + 1) * (OUT_DIM / 2)] = r1;
        }
    }
}

// ---------------------------------------------------------------------------
// Fallback: direct gather from row-major x (only if ws can't hold x_Tb).
// ---------------------------------------------------------------------------
__global__ __launch_bounds__(256) void logic_direct_kernel(
    const void* __restrict__ x_raw,
    const void* __restrict__ idx_raw,
    const float4* __restrict__ coeffs,
    float* __restrict__ out)
{
    __shared__ int sflag;
    int t = threadIdx.x;
    if (t == 0) sflag = 0;
    __syncthreads();
    int fl = 0;
    if (((const unsigned short*)x_raw)[t] >= 0x3F80u) fl |= 1;
    if ((t & 1) && ((const int*)idx_raw)[t] != 0) fl |= 2;
    if (fl) atomicOr(&sflag, fl);
    __syncthreads();
    int x_is_f32   = sflag & 1;
    int idx_is_i32 = (sflag >> 1) & 1;

    int o = blockIdx.x * 256 + t;
    int ia, ib;
    if (idx_is_i32) {
        const int* p = (const int*)idx_raw;
        ia = p[o];       ib = p[OUT_DIM + o];
    } else {
        const long long* p = (const long long*)idx_raw;
        ia = (int)p[o];  ib = (int)p[OUT_DIM + o];
    }
    float4 c = coeffs[o];
    int b0 = blockIdx.y * 32;

    if (x_is_f32) {
        const float* xa = (const float*)x_raw + ia;
        const float* xb = (const float*)x_raw + ib;
        #pragma unroll 8
        for (int r = 0; r < 32; ++r) {
            int b = b0 + r;
            float av = xa[(size_t)b * IN_DIM];
            float bv = xb[(size_t)b * IN_DIM];
            out[(size_t)b * OUT_DIM + o] =
                fmaf(bv, fmaf(c.w, av, c.z), fmaf(c.y, av, c.x));
        }
    } else {
        const unsigned short* xa = (const unsigned short*)x_raw + ia;
        const unsigned short* xb = (const unsigned short*)x_raw + ib;
        #pragma unroll 8
        for (int r = 0; r < 32; ++r) {
            int b = b0 + r;
            float av = bf2f(xa[(size_t)b * IN_DIM]);
            float bv = bf2f(xb[(size_t)b * IN_DIM]);
            out[(size_t)b * OUT_DIM + o] =
                fmaf(bv, fmaf(c.w, av, c.z), fmaf(c.y, av, c.x));
        }
    }
}

extern "C" void kernel_launch(void* const* d_in, const int* in_sizes, int n_in,
                              void* d_out, int out_size, void* d_ws, size_t ws_size,
                              hipStream_t stream) {
    const void* x       = d_in[0];
    const void* weights = d_in[1];
    const void* indices = d_in[2];
    float*      out     = (float*)d_out;

    float4*       coeffs = (float4*)((char*)d_ws + 256);
    unsigned int* x_Tb   = (unsigned int*)((char*)d_ws + 2u * 1024u * 1024u);

    const size_t need = 2u * 1024u * 1024u +
                        (size_t)IN_DIM * (BATCH / 2) * sizeof(unsigned int); // ~34 MiB

    if (ws_size >= need) {
        prep_kernel<<<dim3(TRANS_BLOCKS + COEFF_BLOCKS), dim3(256), 0, stream>>>(
            x, weights, x_Tb, coeffs, TRANS_BLOCKS);
        dim3 grid(OUT_DIM / 512, BATCH / 32);
        logic_bt_kernel<<<grid, dim3(256), 0, stream>>>(
            x_Tb, indices, coeffs, out);
    } else {
        prep_kernel<<<dim3(COEFF_BLOCKS), dim3(256), 0, stream>>>(
            x, weights, x_Tb, coeffs, /*trans_blocks=*/0);
        dim3 grid(OUT_DIM / 256, BATCH / 32);
        logic_direct_kernel<<<grid, dim3(256), 0, stream>>>(
            x, indices, coeffs, out);
    }
}

// Round 7
// 140.153 us; speedup vs baseline: 1.0158x; 1.0158x over previous
//
#include <hip/hip_runtime.h>

#define IN_DIM  65536
#define OUT_DIM 65536
#define BATCH   256

// ws layout: float4 coeffs[OUT_DIM] @256 ; uint x_Tb[IN_DIM * BATCH/2] @2MiB (packed bf16 pairs).

__device__ __forceinline__ float bf2f(unsigned short h) {
    return __uint_as_float(((unsigned int)h) << 16);
}
__device__ __forceinline__ unsigned short f2bf(float f) {
    unsigned int u = __float_as_uint(f);
    u += 0x7FFFu + ((u >> 16) & 1u);
    return (unsigned short)(u >> 16);
}

// Softmax over 16 logits collapsed to affine coeffs of out = w0 + w1*a + w2*b + w3*ab.
__device__ __forceinline__ float4 collapse16(const float* w) {
    float m = w[0];
    #pragma unroll
    for (int f = 1; f < 16; ++f) m = fmaxf(m, w[f]);
    float e[16]; float sum = 0.f;
    #pragma unroll
    for (int f = 0; f < 16; ++f) { e[f] = __expf(w[f] - m); sum += e[f]; }
    float inv = 1.0f / sum;
    float w0 = e[8] + e[9] + e[10] + e[11] + e[12] + e[13] + e[14] + e[15];
    float w1 = (e[2] + e[3] + e[6] + e[7]) - (e[8] + e[9] + e[12] + e[13]);
    float w2 = (e[4] + e[5] + e[6] + e[7]) - (e[8] + e[9] + e[10] + e[11]);
    float w3 = e[1] - e[2] - e[4] - 2.f*e[6] - e[7]
             + e[8] + 2.f*e[9] + e[11] + e[13] - e[14];
    return make_float4(w0 * inv, w1 * inv, w2 * inv, w3 * inv);
}

#define TRANS_BLOCKS ((IN_DIM / 64) * (BATCH / 64))   // 4096
#define COEFF_BLOCKS (OUT_DIM / 256)                  // 256
#define PAD 69   // 69 % 32 = 5 -> column-phase reads are <=2-way (free)

// ---------------------------------------------------------------------------
// Kernel A: fused transpose (x [BATCH,IN_DIM] -> packed-bf16 x_Tb
// [IN_DIM, BATCH/2 dwords]) + per-neuron softmax-collapse coeffs.
// Vectorized: float4/uint2 global loads, uint4 packed stores.
// Each block self-detects the dtype of the input it touches.
// ---------------------------------------------------------------------------
__global__ __launch_bounds__(256) void prep_kernel(
    const void* __restrict__ x_raw,       // [BATCH, IN_DIM] fp32 or bf16
    const void* __restrict__ w_raw,       // [OUT_DIM, 16]   fp32 or bf16
    unsigned int* __restrict__ x_Tb,      // [IN_DIM, BATCH/2] packed bf16
    float4* __restrict__ coeffs,          // [OUT_DIM]
    int trans_blocks)
{
    __shared__ float tile[64][PAD];       // [batch_row][col]
    __shared__ int sflag;
    int t  = threadIdx.x;
    int bx = blockIdx.x;

    if (bx < trans_blocks) {
        if (t == 0) sflag = 0;
        __syncthreads();
        if (((const unsigned short*)x_raw)[t] >= 0x3F80u) atomicOr(&sflag, 1);
        __syncthreads();
        int x_is_f32 = sflag;

        int c0 = (bx >> 2) * 64;   // input-dim tile
        int b0 = (bx & 3) * 64;    // batch tile
        int cq = t & 15;           // float4 col group (4 cols)
        int r  = t >> 4;           // 0..15

        if (x_is_f32) {
            const float4* x4 = (const float4*)x_raw;
            #pragma unroll
            for (int k = 0; k < 4; ++k) {
                int row = r + 16 * k;
                float4 v = x4[(size_t)(b0 + row) * (IN_DIM / 4) + (c0 >> 2) + cq];
                tile[row][4 * cq + 0] = v.x;
                tile[row][4 * cq + 1] = v.y;
                tile[row][4 * cq + 2] = v.z;
                tile[row][4 * cq + 3] = v.w;
            }
        } else {
            const uint2* x2 = (const uint2*)x_raw;  // 4 bf16 per uint2
            #pragma unroll
            for (int k = 0; k < 4; ++k) {
                int row = r + 16 * k;
                uint2 v = x2[(size_t)(b0 + row) * (IN_DIM / 4) + (c0 >> 2) + cq];
                tile[row][4 * cq + 0] = bf2f((unsigned short)(v.x & 0xFFFFu));
                tile[row][4 * cq + 1] = bf2f((unsigned short)(v.x >> 16));
                tile[row][4 * cq + 2] = bf2f((unsigned short)(v.y & 0xFFFFu));
                tile[row][4 * cq + 3] = bf2f((unsigned short)(v.y >> 16));
            }
        }
        __syncthreads();

        // pack columns: per col, 32 dwords (64 batch) = 8 uint4; 512 uint4/tile
        uint4* dst = (uint4*)x_Tb;
        int q   = t & 7;          // uint4 index within col (batch 8q..8q+7)
        int col = t >> 3;         // 0..31, second iter +32
        #pragma unroll
        for (int it = 0; it < 2; ++it) {
            int cc = col + 32 * it;
            unsigned int d[4];
            #pragma unroll
            for (int j = 0; j < 4; ++j) {
                float lo = tile[8 * q + 2 * j][cc];
                float hi = tile[8 * q + 2 * j + 1][cc];
                d[j] = (unsigned int)f2bf(lo) | ((unsigned int)f2bf(hi) << 16);
            }
            dst[(size_t)(c0 + cc) * (BATCH / 8) + (b0 >> 3) + q] =
                make_uint4(d[0], d[1], d[2], d[3]);
        }
    } else {
        // ---- coeff block ----
        if (t == 0) sflag = 0;
        __syncthreads();
        if ((((const unsigned short*)w_raw)[t] & 0x7FFFu) >= 0x4800u) atomicOr(&sflag, 1);
        __syncthreads();
        int w_is_f32 = sflag;

        int o = (bx - trans_blocks) * 256 + t;
        if (o >= OUT_DIM) return;

        float w[16];
        if (w_is_f32) {
            const float4* w4 = reinterpret_cast<const float4*>(w_raw) + (size_t)o * 4;
            float4 q0 = w4[0], q1 = w4[1], q2 = w4[2], q3 = w4[3];
            w[0]=q0.x; w[1]=q0.y; w[2]=q0.z; w[3]=q0.w;
            w[4]=q1.x; w[5]=q1.y; w[6]=q1.z; w[7]=q1.w;
            w[8]=q2.x; w[9]=q2.y; w[10]=q2.z; w[11]=q2.w;
            w[12]=q3.x; w[13]=q3.y; w[14]=q3.z; w[15]=q3.w;
        } else {
            const uint4* w16 = reinterpret_cast<const uint4*>(
                (const unsigned short*)w_raw + (size_t)o * 16);
            uint4 p0 = w16[0], p1 = w16[1];
            unsigned int pk[8] = { p0.x, p0.y, p0.z, p0.w, p1.x, p1.y, p1.z, p1.w };
            #pragma unroll
            for (int i = 0; i < 8; ++i) {
                w[2*i]   = bf2f((unsigned short)(pk[i] & 0xFFFFu));
                w[2*i+1] = bf2f((unsigned short)(pk[i] >> 16));
            }
        }
        coeffs[o] = collapse16(w);
    }
}

// ---------------------------------------------------------------------------
// Kernel B: gather + affine combine from packed-bf16 x_Tb.
// R5 shape (measured best): 1 neuron/thread, 32 batch rows per y-block,
// 4 full-line uint4 gathers per operand. Non-temporal out stores keep the
// streaming 64MiB output from evicting x_Tb out of L2.
// ---------------------------------------------------------------------------
__global__ __launch_bounds__(256) void logic_bt_kernel(
    const unsigned int* __restrict__ x_Tb,  // [IN_DIM, BATCH/2]
    const void* __restrict__ idx_raw,       // [2, OUT_DIM] int32 or int64
    const float4* __restrict__ coeffs,
    float* __restrict__ out)                // [BATCH, OUT_DIM]
{
    __shared__ int sflag;
    int t = threadIdx.x;
    if (t == 0) sflag = 0;
    __syncthreads();
    if ((t & 1) && ((const int*)idx_raw)[t] != 0) atomicOr(&sflag, 1);
    __syncthreads();
    int idx_is_i32 = sflag;   // odd dwords nonzero -> int32

    int o = blockIdx.x * 256 + t;
    int ia, ib;
    if (idx_is_i32) {
        const int* p = (const int*)idx_raw;
        ia = p[o];       ib = p[OUT_DIM + o];
    } else {
        const long long* p = (const long long*)idx_raw;
        ia = (int)p[o];  ib = (int)p[OUT_DIM + o];
    }
    float4 c = coeffs[o];

    int b0 = blockIdx.y * 32;
    const uint4* xa = (const uint4*)x_Tb + ((size_t)ia << 5) + (b0 >> 3);
    const uint4* xb = (const uint4*)x_Tb + ((size_t)ib << 5) + (b0 >> 3);

    #pragma unroll
    for (int r = 0; r < 4; ++r) {
        uint4 ua = xa[r], ub = xb[r];
        unsigned int pa[4] = { ua.x, ua.y, ua.z, ua.w };
        unsigned int pb[4] = { ub.x, ub.y, ub.z, ub.w };
        int base = b0 + r * 8;
        #pragma unroll
        for (int j = 0; j < 4; ++j) {
            float a0 = bf2f((unsigned short)(pa[j] & 0xFFFFu));
            float a1 = bf2f((unsigned short)(pa[j] >> 16));
            float v0 = bf2f((unsigned short)(pb[j] & 0xFFFFu));
            float v1 = bf2f((unsigned short)(pb[j] >> 16));
            float r0 = fmaf(v0, fmaf(c.w, a0, c.z), fmaf(c.y, a0, c.x));
            float r1 = fmaf(v1, fmaf(c.w, a1, c.z), fmaf(c.y, a1, c.x));
            __builtin_nontemporal_store(r0, &out[(size_t)(base + 2*j)     * OUT_DIM + o]);
            __builtin_nontemporal_store(r1, &out[(size_t)(base + 2*j + 1) * OUT_DIM + o]);
        }
    }
}

// ---------------------------------------------------------------------------
// Fallback: direct gather from row-major x (only if ws can't hold x_Tb).
// ---------------------------------------------------------------------------
__global__ __launch_bounds__(256) void logic_direct_kernel(
    const void* __restrict__ x_raw,
    const void* __restrict__ idx_raw,
    const float4* __restrict__ coeffs,
    float* __restrict__ out)
{
    __shared__ int sflag;
    int t = threadIdx.x;
    if (t == 0) sflag = 0;
    __syncthreads();
    int fl = 0;
    if (((const unsigned short*)x_raw)[t] >= 0x3F80u) fl |= 1;
    if ((t & 1) && ((const int*)idx_raw)[t] != 0) fl |= 2;
    if (fl) atomicOr(&sflag, fl);
    __syncthreads();
    int x_is_f32   = sflag & 1;
    int idx_is_i32 = (sflag >> 1) & 1;

    int o = blockIdx.x * 256 + t;
    int ia, ib;
    if (idx_is_i32) {
        const int* p = (const int*)idx_raw;
        ia = p[o];       ib = p[OUT_DIM + o];
    } else {
        const long long* p = (const long long*)idx_raw;
        ia = (int)p[o];  ib = (int)p[OUT_DIM + o];
    }
    float4 c = coeffs[o];
    int b0 = blockIdx.y * 32;

    if (x_is_f32) {
        const float* xa = (const float*)x_raw + ia;
        const float* xb = (const float*)x_raw + ib;
        #pragma unroll 8
        for (int r = 0; r < 32; ++r) {
            int b = b0 + r;
            float av = xa[(size_t)b * IN_DIM];
            float bv = xb[(size_t)b * IN_DIM];
            out[(size_t)b * OUT_DIM + o] =
                fmaf(bv, fmaf(c.w, av, c.z), fmaf(c.y, av, c.x));
        }
    } else {
        const unsigned short* xa = (const unsigned short*)x_raw + ia;
        const unsigned short* xb = (const unsigned short*)x_raw + ib;
        #pragma unroll 8
        for (int r = 0; r < 32; ++r) {
            int b = b0 + r;
            float av = bf2f(xa[(size_t)b * IN_DIM]);
            float bv = bf2f(xb[(size_t)b * IN_DIM]);
            out[(size_t)b * OUT_DIM + o] =
                fmaf(bv, fmaf(c.w, av, c.z), fmaf(c.y, av, c.x));
        }
    }
}

extern "C" void kernel_launch(void* const* d_in, const int* in_sizes, int n_in,
                              void* d_out, int out_size, void* d_ws, size_t ws_size,
                              hipStream_t stream) {
    const void* x       = d_in[0];
    const void* weights = d_in[1];
    const void* indices = d_in[2];
    float*      out     = (float*)d_out;

    float4*       coeffs = (float4*)((char*)d_ws + 256);
    unsigned int* x_Tb   = (unsigned int*)((char*)d_ws + 2u * 1024u * 1024u);

    const size_t need = 2u * 1024u * 1024u +
                        (size_t)IN_DIM * (BATCH / 2) * sizeof(unsigned int); // ~34 MiB

    if (ws_size >= need) {
        prep_kernel<<<dim3(TRANS_BLOCKS + COEFF_BLOCKS), dim3(256), 0, stream>>>(
            x, weights, x_Tb, coeffs, TRANS_BLOCKS);
        dim3 grid(OUT_DIM / 256, BATCH / 32);
        logic_bt_kernel<<<grid, dim3(256), 0, stream>>>(
            x_Tb, indices, coeffs, out);
    } else {
        prep_kernel<<<dim3(COEFF_BLOCKS), dim3(256), 0, stream>>>(
            x, weights, x_Tb, coeffs, /*trans_blocks=*/0);
        dim3 grid(OUT_DIM / 256, BATCH / 32);
        logic_direct_kernel<<<grid, dim3(256), 0, stream>>>(
            x, indices, coeffs, out);
    }
}